// Round 2
// baseline (328.556 us; speedup 1.0000x reference)
//
#include <hip/hip_runtime.h>
#include <hip/hip_bf16.h>
#include <cstdint>
#include <cstddef>

// Inputs/outputs are FP32 (per reference). Compute path: fp32 -> bf16 -> MFMA
// (fp32 accumulate) -> fp32 out. Threshold 7.81e-2 permits bf16 compute.
typedef unsigned short u16;
typedef __attribute__((ext_vector_type(8))) __bf16 bf16x8;
typedef __attribute__((ext_vector_type(4))) float f32x4;

__device__ __forceinline__ void gload_lds16(const void* g, void* l) {
    // async global->LDS, 16B per lane; LDS dest = wave-uniform base + lane*16
    __builtin_amdgcn_global_load_lds(
        (const __attribute__((address_space(1))) unsigned int*)g,
        (__attribute__((address_space(3))) unsigned int*)l,
        16, 0, 0);
}

__device__ __forceinline__ u16 f2bf(float f) {  // RNE
    union { float f; unsigned int u; } v; v.f = f;
    unsigned int r = v.u + 0x7fffu + ((v.u >> 16) & 1u);
    return (u16)(r >> 16);
}

// C = act(A @ Bt^T + bias). A: MxK row-major bf16. Bt: NxK row-major bf16
// (K-contiguous). bias fp32. OUT_BF16 ? C bf16 : C fp32. M%128==0, N%128==0,
// K%32==0. m97 structure: 128x128 tile, BK=32, 4 waves 2x2, 4x4 acc/wave.
template <int GELU, int OUT_BF16>
__global__ void gemm_bt_bias_act(const u16* __restrict__ A,
                                 const u16* __restrict__ Bt,
                                 const float* __restrict__ bias,
                                 void* __restrict__ Cv,
                                 int M, int N, int K) {
    __shared__ u16 As[128 * 32];  // [m][k] k-contiguous
    __shared__ u16 Bs[128 * 32];  // [n][k] k-contiguous

    const int tid  = threadIdx.x;          // 256 threads
    const int lane = tid & 63;
    const int wave = tid >> 6;
    const int wm   = (wave >> 1) * 64;
    const int wn   = (wave & 1) * 64;
    const int mrow = lane & 15;            // m (or n) within 16x16 tile
    const int half = lane >> 4;            // k-group 0..3

    const size_t ldb = (size_t)K * 2;      // row stride in bytes
    const char* Ab = (const char*)(A + (size_t)blockIdx.x * 128 * K);
    const char* Bb = (const char*)(Bt + (size_t)blockIdx.y * 128 * K);

    // staging: 8 KB per tile = 512 lanes*16B -> 2 instructions/thread/tile
    const int lin0 = tid, lin1 = tid + 256;
    const size_t aoff0 = (size_t)(lin0 >> 2) * ldb + ((lin0 & 3) << 4);
    const size_t aoff1 = (size_t)(lin1 >> 2) * ldb + ((lin1 & 3) << 4);

    f32x4 acc[4][4];
#pragma unroll
    for (int i = 0; i < 4; ++i)
#pragma unroll
        for (int j = 0; j < 4; ++j) acc[i][j] = f32x4{0.f, 0.f, 0.f, 0.f};

    for (int k0 = 0; k0 < K; k0 += 32) {
        const size_t kb = (size_t)k0 * 2;
        gload_lds16(Ab + aoff0 + kb, (char*)As + lin0 * 16);
        gload_lds16(Ab + aoff1 + kb, (char*)As + lin1 * 16);
        gload_lds16(Bb + aoff0 + kb, (char*)Bs + lin0 * 16);
        gload_lds16(Bb + aoff1 + kb, (char*)Bs + lin1 * 16);
        __syncthreads();  // compiler drains vmcnt(0) before s_barrier

        bf16x8 af[4], bfr[4];
#pragma unroll
        for (int t = 0; t < 4; ++t)
            af[t] = *(const bf16x8*)(As + (wm + t * 16 + mrow) * 32 + half * 8);
#pragma unroll
        for (int t = 0; t < 4; ++t)
            bfr[t] = *(const bf16x8*)(Bs + (wn + t * 16 + mrow) * 32 + half * 8);

#pragma unroll
        for (int mi = 0; mi < 4; ++mi)
#pragma unroll
            for (int ni = 0; ni < 4; ++ni)
                acc[mi][ni] = __builtin_amdgcn_mfma_f32_16x16x32_bf16(
                    af[mi], bfr[ni], acc[mi][ni], 0, 0, 0);
        __syncthreads();  // all LDS reads done before next stage overwrites
    }

    // C/D layout (m89-verified): col = lane&15, row = (lane>>4)*4 + reg
    const int row0 = blockIdx.x * 128 + wm + half * 4;
    const int col0 = blockIdx.y * 128 + wn + mrow;
#pragma unroll
    for (int ni = 0; ni < 4; ++ni) {
        const int col = col0 + ni * 16;
        const float bv = bias[col];
#pragma unroll
        for (int mi = 0; mi < 4; ++mi) {
            const int row = row0 + mi * 16;
#pragma unroll
            for (int r = 0; r < 4; ++r) {
                float v = acc[mi][ni][r] + bv;
                if (GELU) v = 0.5f * v * (1.0f + erff(v * 0.70710678118654752f));
                if (OUT_BF16)
                    ((u16*)Cv)[(size_t)(row + r) * N + col] = f2bf(v);
                else
                    ((float*)Cv)[(size_t)(row + r) * N + col] = v;
            }
        }
    }
}

// dst[c][r] = bf16(src[r][c]); src fp32 R x C, dst bf16 C x R. R,C %32==0.
__global__ void transpose_cvt_bf16(const float* __restrict__ src,
                                   u16* __restrict__ dst, int R, int C) {
    __shared__ u16 t[32][33];
    const int bx = blockIdx.x * 32;  // col offset in src
    const int by = blockIdx.y * 32;  // row offset in src
    const int x = threadIdx.x, y = threadIdx.y;  // 32 x 8
    for (int i = 0; i < 32; i += 8)
        t[y + i][x] = f2bf(src[(size_t)(by + y + i) * C + (bx + x)]);
    __syncthreads();
    for (int i = 0; i < 32; i += 8)
        dst[(size_t)(bx + y + i) * R + (by + x)] = t[x][y + i];
}

// flat fp32 -> bf16, n % 1024 == 0
__global__ void cvt_bf16(const float* __restrict__ src, u16* __restrict__ dst,
                         long long n) {
    const long long i = ((long long)blockIdx.x * blockDim.x + threadIdx.x) * 4;
    if (i + 3 < n) {
        const float4 v = *(const float4*)(src + i);
        ushort4 o;
        o.x = f2bf(v.x); o.y = f2bf(v.y); o.z = f2bf(v.z); o.w = f2bf(v.w);
        *(ushort4*)(dst + i) = o;
    }
}

// out[b, 0, :] = hs[b, 0, :]  (fp32)
__global__ void fixup_first_token(const float* __restrict__ hs,
                                  float* __restrict__ out, int S, int D) {
    const size_t base = (size_t)blockIdx.x * S * D;
    for (int i = threadIdx.x; i < D; i += blockDim.x)
        out[base + i] = hs[base + i];
}

extern "C" void kernel_launch(void* const* d_in, const int* in_sizes, int n_in,
                              void* d_out, int out_size, void* d_ws, size_t ws_size,
                              hipStream_t stream) {
    const float* X  = (const float*)d_in[0];  // [B,S,D] fp32
    const float* W1 = (const float*)d_in[1];  // [D,H]
    const float* b1 = (const float*)d_in[2];  // [H]
    const float* W2 = (const float*)d_in[3];  // [H,D]
    const float* b2 = (const float*)d_in[4];  // [D]
    float* out = (float*)d_out;

    const int B = 8, S = 2048, D = 1024, H = 2048;
    const int M = B * S;  // 16384

    // ws: W1T bf16 HxD (4MB) | W2T bf16 DxH (4MB) | Xb bf16 CMxD | Hb bf16 CMxH
    u16* W1T = (u16*)d_ws;
    u16* W2T = W1T + (size_t)H * D;
    u16* Xb  = W2T + (size_t)D * H;
    const size_t wfixed = (size_t)H * D * 2 * 2;  // 8 MB
    const size_t perrow = (size_t)(D + H) * 2;    // 6 KB/row
    size_t avail_rows = (ws_size > wfixed) ? (ws_size - wfixed) / perrow : 0;
    int CM = (int)((avail_rows / 128) * 128);
    if (CM > M) CM = M;
    if (CM < 128) CM = 128;
    u16* Hb = Xb + (size_t)CM * D;

    dim3 tb(32, 8);
    transpose_cvt_bf16<<<dim3(H / 32, D / 32), tb, 0, stream>>>(W1, W1T, D, H);
    transpose_cvt_bf16<<<dim3(D / 32, H / 32), tb, 0, stream>>>(W2, W2T, H, D);

    for (int m0 = 0; m0 < M; m0 += CM) {
        const int rows = (M - m0 < CM) ? (M - m0) : CM;
        const long long n = (long long)rows * D;
        cvt_bf16<<<dim3((unsigned)(n / 1024)), dim3(256), 0, stream>>>(
            X + (size_t)m0 * D, Xb, n);
        dim3 g1(rows / 128, H / 128);
        gemm_bt_bias_act<1, 1><<<g1, dim3(256), 0, stream>>>(
            Xb, W1T, b1, Hb, rows, H, D);
        dim3 g2(rows / 128, D / 128);
        gemm_bt_bias_act<0, 0><<<g2, dim3(256), 0, stream>>>(
            Hb, W2T, b2, out + (size_t)m0 * D, rows, D, H);
    }

    fixup_first_token<<<dim3(B), dim3(256), 0, stream>>>(X, out, S, D);
}